// Round 1
// baseline (5373.050 us; speedup 1.0000x reference)
//
#include <hip/hip_runtime.h>
#include <hip/hip_bf16.h>
#include <math.h>

#ifndef M_PI
#define M_PI 3.14159265358979323846
#endif

typedef unsigned short u16;

#define NB   16
#define CIN  256
#define CH   128
#define HW   10000
#define NA   100
#define NR   100

__device__ __forceinline__ float bf2f(u16 v) {
  return __uint_as_float(((unsigned int)v) << 16);
}
__device__ __forceinline__ u16 f2bf(float f) {
  unsigned int u = __float_as_uint(f);
  u += 0x7fffu + ((u >> 16) & 1u);   // round-to-nearest-even
  return (u16)(u >> 16);
}

// ---------------------------------------------------------------------------
// prep: weight transposes + per-angle cos/sin table (float64, matches numpy)
//   w1t[k][c]        = w1[c][k]
//   w2t/w3t[tap][ci][co] = w[co][ci][tap]
// ---------------------------------------------------------------------------
__global__ void k_prep(const float* __restrict__ w1, const float* __restrict__ w2,
                       const float* __restrict__ w3, float* __restrict__ w1t,
                       float* __restrict__ w2t, float* __restrict__ w3t,
                       double* __restrict__ trig) {
  int t = blockIdx.x * blockDim.x + threadIdx.x;
  if (t < NA) {
#pragma clang fp contract(off)
    double theta = (double)t * (M_PI / 100.0);
    double irho  = 142.0 / 99.0;   // (floor(sqrt(2*100^2))+1)/(numRho-1)
    trig[2 * t]     = cos(theta) / irho;
    trig[2 * t + 1] = sin(theta) / irho;
  }
  if (t < CIN * CH) {
    int k = t / CH, c = t % CH;
    w1t[t] = w1[c * CIN + k];
  }
  if (t < 9 * CH * CH) {
    int tap = t / (CH * CH);
    int rem = t - tap * (CH * CH);
    int ci = rem / CH, co = rem & (CH - 1);
    w2t[t] = w2[(co * CH + ci) * 9 + tap];
    w3t[t] = w3[(co * CH + ci) * 9 + tap];
  }
}

// ---------------------------------------------------------------------------
// idx[a][p] = clip(rint(xx*cos_t + yy*sin_t) + 50, 0, 99)   (exact f64, no fma)
// ---------------------------------------------------------------------------
__global__ void k_idx(const double* __restrict__ trig, int* __restrict__ idx) {
#pragma clang fp contract(off)
  int a = blockIdx.y;
  int p = blockIdx.x * blockDim.x + threadIdx.x;
  if (p >= HW) return;
  double ct = trig[2 * a], st = trig[2 * a + 1];
  int i = p / 100;
  int j = p - i * 100;
  double s = (double)(j - 50) * ct + (double)(i - 50) * st;
  int r = (int)rint(s) + 50;
  r = r < 0 ? 0 : (r > 99 ? 99 : r);
  idx[a * HW + p] = r;
}

// ---------------------------------------------------------------------------
// conv1: 1x1 conv (CIN=256 -> CH=128) + BN + ReLU, x[N][CIN][HW] f32
//   -> h1t[N][HW][CH] bf16.  Block: 64 m x 128 c, thread: 8m x 4c.
// ---------------------------------------------------------------------------
__global__ void __launch_bounds__(256)
k_conv1(const float* __restrict__ x, const float* __restrict__ w1t,
        const float* __restrict__ pb, const float* __restrict__ pg,
        const float* __restrict__ pbe, u16* __restrict__ h1t) {
  __shared__ float xT[32][64];
  __shared__ float wT[32][128];
  int n  = blockIdx.y;
  int m0 = blockIdx.x * 64;
  int t  = threadIdx.x;
  int tx = t & 31;   // c-group: c0 = tx*4
  int ty = t >> 5;   // m-group: m = m0 + ty*8 + i
  float acc[8][4] = {};

  for (int k0 = 0; k0 < CIN; k0 += 32) {
#pragma unroll
    for (int q = 0; q < 8; ++q) {           // stage x: 32k x 64m
      int e = t + q * 256;
      int kk = e >> 6, mm = e & 63;
      int hw = m0 + mm;
      xT[kk][mm] = (hw < HW) ? x[((size_t)n * CIN + k0 + kk) * HW + hw] : 0.f;
    }
#pragma unroll
    for (int q = 0; q < 16; ++q) {          // stage w: 32k x 128c
      int e = t + q * 256;
      int kk = e >> 7, cc = e & 127;
      wT[kk][cc] = w1t[(size_t)(k0 + kk) * CH + cc];
    }
    __syncthreads();
#pragma unroll
    for (int kk = 0; kk < 32; ++kk) {
      float4 wv = *(const float4*)&wT[kk][tx * 4];
      float xv[8];
      *(float4*)&xv[0] = *(const float4*)&xT[kk][ty * 8];
      *(float4*)&xv[4] = *(const float4*)&xT[kk][ty * 8 + 4];
#pragma unroll
      for (int i = 0; i < 8; ++i) {
        acc[i][0] += xv[i] * wv.x;
        acc[i][1] += xv[i] * wv.y;
        acc[i][2] += xv[i] * wv.z;
        acc[i][3] += xv[i] * wv.w;
      }
    }
    __syncthreads();
  }

  int c0 = tx * 4;
  float sc[4], sh[4];
#pragma unroll
  for (int jj = 0; jj < 4; ++jj) {
    float s = pg[c0 + jj] / sqrtf(1.f + 1e-5f);
    sc[jj] = s;
    sh[jj] = pb[c0 + jj] * s + pbe[c0 + jj];
  }
#pragma unroll
  for (int i = 0; i < 8; ++i) {
    int m = m0 + ty * 8 + i;
    if (m < HW) {
      ushort4 pk;
      float y0 = fmaxf(acc[i][0] * sc[0] + sh[0], 0.f);
      float y1 = fmaxf(acc[i][1] * sc[1] + sh[1], 0.f);
      float y2 = fmaxf(acc[i][2] * sc[2] + sh[2], 0.f);
      float y3 = fmaxf(acc[i][3] * sc[3] + sh[3], 0.f);
      pk.x = f2bf(y0); pk.y = f2bf(y1); pk.z = f2bf(y2); pk.w = f2bf(y3);
      *(ushort4*)&h1t[((size_t)n * HW + m) * CH + c0] = pk;
    }
  }
}

// ---------------------------------------------------------------------------
// dht: block = (n, angle-pair). lanes = channels. f32 bins in LDS, run-length
// compressed scatter. h1t[N][HW][CH] bf16 -> dht[N][A][R][CH] bf16
// ---------------------------------------------------------------------------
__global__ void __launch_bounds__(256)
k_dht(const u16* __restrict__ h1t, const int* __restrict__ idx,
      u16* __restrict__ dht) {
  __shared__ float bins[2][NR][CH];   // 102.4 KB
  int n  = blockIdx.y;
  int a0 = blockIdx.x * 2;
  int t  = threadIdx.x;
  int c  = t & 127;
  int g  = t >> 7;
  int a  = a0 + g;

  for (int q = t; q < 2 * NR * CH; q += 256) ((float*)bins)[q] = 0.f;
  __syncthreads();

  const int4* idxr = (const int4*)(idx + a * HW);
  const u16*  img  = h1t + (size_t)n * HW * CH + c;

  int   rc  = -1;
  float acc = 0.f;
  for (int p0 = 0; p0 < HW; p0 += 4) {
    int4 r4 = idxr[p0 >> 2];
    u16 v0 = img[(size_t)(p0 + 0) * CH];
    u16 v1 = img[(size_t)(p0 + 1) * CH];
    u16 v2 = img[(size_t)(p0 + 2) * CH];
    u16 v3 = img[(size_t)(p0 + 3) * CH];
    int rr[4];
    rr[0] = __builtin_amdgcn_readfirstlane(r4.x);
    rr[1] = __builtin_amdgcn_readfirstlane(r4.y);
    rr[2] = __builtin_amdgcn_readfirstlane(r4.z);
    rr[3] = __builtin_amdgcn_readfirstlane(r4.w);
    float vv[4] = {bf2f(v0), bf2f(v1), bf2f(v2), bf2f(v3)};
#pragma unroll
    for (int u = 0; u < 4; ++u) {
      if (rr[u] != rc) {
        if (rc >= 0) bins[g][rc][c] += acc;
        rc  = rr[u];
        acc = vv[u];
      } else {
        acc += vv[u];
      }
    }
  }
  if (rc >= 0) bins[g][rc][c] += acc;
  __syncthreads();

  for (int q = t; q < 2 * NR * CH; q += 256) {
    int gg  = q / (NR * CH);
    int rem = q - gg * (NR * CH);
    int r   = rem >> 7;
    int cc  = rem & 127;
    dht[(((size_t)n * NA + a0 + gg) * NR + r) * CH + cc] = f2bf(bins[gg][r][cc]);
  }
}

// ---------------------------------------------------------------------------
// 3x3 conv + BN + ReLU over [A,R] spatial, channels-innermost bf16 input.
// OUT_MODE 0: bf16 [N][A][R][CH];  OUT_MODE 1: f32 [N][CH][A][R] (final)
// ---------------------------------------------------------------------------
template <int OUT_MODE>
__global__ void __launch_bounds__(256)
k_conv3x3(const u16* __restrict__ X, const float* __restrict__ wt,
          const float* __restrict__ pb, const float* __restrict__ pg,
          const float* __restrict__ pbe, void* __restrict__ out) {
  __shared__ float patch[32][68];
  __shared__ float wT[32][128];
  int n  = blockIdx.y;
  int m0 = blockIdx.x * 64;
  int t  = threadIdx.x;
  int tx = t & 31;
  int ty = t >> 5;
  float acc[8][4] = {};

  // staging geometry (thread t stages column ci=t&31, rows mm = ty + 8q)
  int av[8], rv[8], vld[8];
#pragma unroll
  for (int q = 0; q < 8; ++q) {
    int mm = ty + 8 * q;
    int m  = m0 + mm;
    av[q]  = m / 100;
    rv[q]  = m - av[q] * 100;
    vld[q] = (m < HW);
  }
  const size_t nbase = (size_t)n * NA * NR * CH;

  for (int tap = 0; tap < 9; ++tap) {
    int da = tap / 3 - 1, dr = tap - (tap / 3) * 3 - 1;
    for (int k0 = 0; k0 < CH; k0 += 32) {
#pragma unroll
      for (int q = 0; q < 8; ++q) {
        int aa = av[q] + da, rr = rv[q] + dr;
        float val = 0.f;
        if (vld[q] && aa >= 0 && aa < NA && rr >= 0 && rr < NR)
          val = bf2f(X[nbase + ((size_t)aa * NR + rr) * CH + k0 + tx]);
        patch[tx][ty + 8 * q] = val;
      }
#pragma unroll
      for (int q = 0; q < 16; ++q) {
        int e = t + q * 256;
        int kk = e >> 7, cc = e & 127;
        wT[kk][cc] = wt[((size_t)tap * CH + k0 + kk) * CH + cc];
      }
      __syncthreads();
#pragma unroll
      for (int kk = 0; kk < 32; ++kk) {
        float4 wv = *(const float4*)&wT[kk][tx * 4];
        float xv[8];
        *(float4*)&xv[0] = *(const float4*)&patch[kk][ty * 8];
        *(float4*)&xv[4] = *(const float4*)&patch[kk][ty * 8 + 4];
#pragma unroll
        for (int i = 0; i < 8; ++i) {
          acc[i][0] += xv[i] * wv.x;
          acc[i][1] += xv[i] * wv.y;
          acc[i][2] += xv[i] * wv.z;
          acc[i][3] += xv[i] * wv.w;
        }
      }
      __syncthreads();
    }
  }

  int c0 = tx * 4;
  float sc[4], sh[4];
#pragma unroll
  for (int jj = 0; jj < 4; ++jj) {
    float s = pg[c0 + jj] / sqrtf(1.f + 1e-5f);
    sc[jj] = s;
    sh[jj] = pb[c0 + jj] * s + pbe[c0 + jj];
  }
#pragma unroll
  for (int i = 0; i < 8; ++i) {
    int m = m0 + ty * 8 + i;
    if (m >= HW) continue;
    float y[4];
#pragma unroll
    for (int jj = 0; jj < 4; ++jj) y[jj] = fmaxf(acc[i][jj] * sc[jj] + sh[jj], 0.f);
    if (OUT_MODE == 0) {
      u16* o = (u16*)out;
      ushort4 pk;
      pk.x = f2bf(y[0]); pk.y = f2bf(y[1]); pk.z = f2bf(y[2]); pk.w = f2bf(y[3]);
      *(ushort4*)&o[((size_t)n * HW + m) * CH + c0] = pk;
    } else {
      float* o = (float*)out;
#pragma unroll
      for (int jj = 0; jj < 4; ++jj)
        o[((size_t)n * CH + c0 + jj) * HW + m] = y[jj];
    }
  }
}

// ---------------------------------------------------------------------------
extern "C" void kernel_launch(void* const* d_in, const int* in_sizes, int n_in,
                              void* d_out, int out_size, void* d_ws, size_t ws_size,
                              hipStream_t stream) {
  if (n_in < 13) return;
  const float* x   = (const float*)d_in[0];
  const float* w1  = (const float*)d_in[1];
  const float* b1  = (const float*)d_in[2];
  const float* g1  = (const float*)d_in[3];
  const float* be1 = (const float*)d_in[4];
  const float* w2  = (const float*)d_in[5];
  const float* b2  = (const float*)d_in[6];
  const float* g2  = (const float*)d_in[7];
  const float* be2 = (const float*)d_in[8];
  const float* w3  = (const float*)d_in[9];
  const float* b3  = (const float*)d_in[10];
  const float* g3  = (const float*)d_in[11];
  const float* be3 = (const float*)d_in[12];

  // workspace layout (all 256B-aligned)
  const size_t o_trig = 0;                         // 100*2*8   = 1600 (pad 2048)
  const size_t o_idx  = 2048;                      // 4,000,000
  const size_t o_w1t  = o_idx + 4000000;           // 131,072
  const size_t o_w2t  = o_w1t + 131072;            // 589,824
  const size_t o_w3t  = o_w2t + 589824;            // 589,824
  const size_t o_dht  = o_w3t + 589824;            // 40,960,000
  const size_t o_c2   = o_dht + 40960000;          // 40,960,000
  const size_t need   = o_c2 + 40960000;           // ~87.2 MB
  if (ws_size < need) return;

  char*   ws   = (char*)d_ws;
  double* trig = (double*)(ws + o_trig);
  int*    idx  = (int*)(ws + o_idx);
  float*  w1t  = (float*)(ws + o_w1t);
  float*  w2t  = (float*)(ws + o_w2t);
  float*  w3t  = (float*)(ws + o_w3t);
  u16*    dht  = (u16*)(ws + o_dht);
  u16*    c2   = (u16*)(ws + o_c2);
  u16*    h1t  = (u16*)d_out;   // 41 MB bf16 scratch inside the 82 MB f32 out
                                // (dead before conv3 overwrites d_out)

  k_prep<<<dim3(576), dim3(256), 0, stream>>>(w1, w2, w3, w1t, w2t, w3t, trig);
  k_idx<<<dim3(40, 100), dim3(256), 0, stream>>>(trig, idx);
  k_conv1<<<dim3(157, 16), dim3(256), 0, stream>>>(x, w1t, b1, g1, be1, h1t);
  k_dht<<<dim3(50, 16), dim3(256), 0, stream>>>(h1t, idx, dht);
  k_conv3x3<0><<<dim3(157, 16), dim3(256), 0, stream>>>(dht, w2t, b2, g2, be2, (void*)c2);
  k_conv3x3<1><<<dim3(157, 16), dim3(256), 0, stream>>>(c2, w3t, b3, g3, be3, d_out);
}